// Round 1
// baseline (2462.124 us; speedup 1.0000x reference)
//
#include <hip/hip_runtime.h>
#include <cstddef>

// Problem constants (from reference): B,L,H,E,N,TR,K
constexpr int B_  = 2;
constexpr int L_  = 1024;
constexpr int H_  = 2048;
constexpr int E_  = 4096;
constexpr int N_  = 16;
constexpr int TR_ = 128;
constexpr int M_  = B_ * L_;        // 2048 token rows
constexpr int P2E = 2 * E_;         // 8192  (proj leading dim)
constexpr int SLD = TR_ + 2 * N_;   // 160   (ssm_p leading dim)

__device__ __forceinline__ float siluf(float x) { return x / (1.f + expf(-x)); }
__device__ __forceinline__ float softplusf(float x) {
  // logaddexp(x,0) = max(x,0) + log1p(exp(-|x|))
  return fmaxf(x, 0.f) + log1pf(expf(-fabsf(x)));
}

// ---------------------------------------------------------------------------
// Generic fp32 tiled GEMM: C[M,N] = A[M,K] @ B[K,N]
//   256 threads, 16x16 thread grid, each thread TMxTN.
//   EPI: 0 = plain store, 1 = softplus(acc + bias[n]) (TN==4), 2 = atomicAdd
//   Split-K via blockIdx.z * kchunk (EPI==2 path).
// All tile dims divide the problem dims exactly (checked at launch site).
// ---------------------------------------------------------------------------
template<int BM, int BN, int BK, int TM, int TN, int EPI>
__global__ __launch_bounds__(256) void sgemm_k(
    const float* __restrict__ A, const float* __restrict__ B,
    float* __restrict__ C, int lda, int ldb, int ldc,
    const float* __restrict__ bias, int kchunk)
{
  __shared__ float As[BK][BM + 4];   // transposed A tile, +4 pad: bank spread, 16B-aligned rows
  __shared__ float Bs[BK][BN];
  const int tid = threadIdx.x;
  const int tx  = tid & 15;          // 16 threads along N
  const int ty  = tid >> 4;          // 16 threads along M
  const int m0  = blockIdx.y * BM;
  const int n0  = blockIdx.x * BN;
  const int k00 = blockIdx.z * kchunk;

  float acc[TM][TN];
#pragma unroll
  for (int i = 0; i < TM; ++i)
#pragma unroll
    for (int j = 0; j < TN; ++j) acc[i][j] = 0.f;

  for (int k0 = k00; k0 < k00 + kchunk; k0 += BK) {
    // stage A tile (BM x BK) -> As[k][m]
    constexpr int A4 = BM * BK / 4;
#pragma unroll
    for (int it = 0; it < (A4 + 255) / 256; ++it) {
      int i = it * 256 + tid;
      if ((A4 % 256 == 0) || (i < A4)) {
        int row = i / (BK / 4);
        int kc  = (i % (BK / 4)) * 4;
        float4 v = *reinterpret_cast<const float4*>(
            A + (size_t)(m0 + row) * lda + k0 + kc);
        As[kc + 0][row] = v.x;
        As[kc + 1][row] = v.y;
        As[kc + 2][row] = v.z;
        As[kc + 3][row] = v.w;
      }
    }
    // stage B tile (BK x BN) -> Bs[k][n]
    constexpr int B4 = BK * BN / 4;
#pragma unroll
    for (int it = 0; it < (B4 + 255) / 256; ++it) {
      int i = it * 256 + tid;
      if ((B4 % 256 == 0) || (i < B4)) {
        int kr = i / (BN / 4);
        int nc = (i % (BN / 4)) * 4;
        *reinterpret_cast<float4*>(&Bs[kr][nc]) =
            *reinterpret_cast<const float4*>(
                B + (size_t)(k0 + kr) * ldb + n0 + nc);
      }
    }
    __syncthreads();
#pragma unroll
    for (int k = 0; k < BK; ++k) {
      float a[TM], bb[TN];
      const float* ap = &As[k][ty * TM];
      if constexpr (TM == 8) {
        float4 a0 = *reinterpret_cast<const float4*>(ap);
        float4 a1 = *reinterpret_cast<const float4*>(ap + 4);
        a[0]=a0.x; a[1]=a0.y; a[2]=a0.z; a[3]=a0.w;
        a[4]=a1.x; a[5]=a1.y; a[6]=a1.z; a[7]=a1.w;
      } else {
        float4 a0 = *reinterpret_cast<const float4*>(ap);
        a[0]=a0.x; a[1]=a0.y; a[2]=a0.z; a[3]=a0.w;
      }
      const float* bp = &Bs[k][tx * TN];
      if constexpr (TN == 4) {
        float4 b0 = *reinterpret_cast<const float4*>(bp);
        bb[0]=b0.x; bb[1]=b0.y; bb[2]=b0.z; bb[3]=b0.w;
      } else {
        float2 b0 = *reinterpret_cast<const float2*>(bp);
        bb[0]=b0.x; bb[1]=b0.y;
      }
#pragma unroll
      for (int i = 0; i < TM; ++i)
#pragma unroll
        for (int j = 0; j < TN; ++j) acc[i][j] = fmaf(a[i], bb[j], acc[i][j]);
    }
    __syncthreads();
  }

#pragma unroll
  for (int i = 0; i < TM; ++i) {
    int row = m0 + ty * TM + i;
    float* crow = C + (size_t)row * ldc + n0 + tx * TN;
    if constexpr (EPI == 2) {
#pragma unroll
      for (int j = 0; j < TN; ++j) atomicAdd(&crow[j], acc[i][j]);
    } else if constexpr (EPI == 1) {
      const float* brow = bias + n0 + tx * TN;
      float4 v;
      v.x = softplusf(acc[i][0] + brow[0]);
      v.y = softplusf(acc[i][1] + brow[1]);
      v.z = softplusf(acc[i][2] + brow[2]);
      v.w = softplusf(acc[i][3] + brow[3]);
      *reinterpret_cast<float4*>(crow) = v;
    } else {
      if constexpr (TN == 4) {
        float4 v; v.x=acc[i][0]; v.y=acc[i][1]; v.z=acc[i][2]; v.w=acc[i][3];
        *reinterpret_cast<float4*>(crow) = v;
      } else {
#pragma unroll
        for (int j = 0; j < TN; ++j) crow[j] = acc[i][j];
      }
    }
  }
}

// ---------------------------------------------------------------------------
// Depthwise causal conv1d (K=4) + bias + SiLU.
//   proj layout: [m, 0:2E]; hidden = first E columns. out hc: [m, e].
//   x[b,e,l] = sum_{k=0..3} hidden[b,e,l-3+k] * ck[e,k]
// ---------------------------------------------------------------------------
__global__ __launch_bounds__(256) void conv_silu_k(
    const float* __restrict__ proj, const float* __restrict__ ck,
    const float* __restrict__ cb, float* __restrict__ hc)
{
  const int idx = blockIdx.x * 256 + threadIdx.x;   // m*E + e
  const int e = idx & (E_ - 1);
  const int m = idx >> 12;                          // / E_ (=4096)
  const int l = m & (L_ - 1);
  const float c0 = ck[e * 4 + 0], c1 = ck[e * 4 + 1];
  const float c2 = ck[e * 4 + 2], c3 = ck[e * 4 + 3];
  const float* pcol = proj + (size_t)m * P2E + e;
  float acc = cb[e];
  if (l >= 3) acc = fmaf(pcol[-3 * P2E], c0, acc);
  if (l >= 2) acc = fmaf(pcol[-2 * P2E], c1, acc);
  if (l >= 1) acc = fmaf(pcol[-1 * P2E], c2, acc);
  acc = fmaf(pcol[0], c3, acc);
  hc[(size_t)m * E_ + e] = siluf(acc);
}

// ---------------------------------------------------------------------------
// Selective scan, fused with discretization, D-skip and gate-SiLU.
//   16 lanes = one (b,e) pair, lane n holds state[n]. Shuffle-reduce over n.
//   y[m,e] = (sum_n state*Cm + hc*D[e]) * silu(gate)
// ---------------------------------------------------------------------------
__global__ __launch_bounds__(256) void scan_k(
    const float* __restrict__ hc, const float* __restrict__ ssm,
    const float* __restrict__ proj, const float* __restrict__ A_log,
    const float* __restrict__ Dvec, const float* __restrict__ dts,
    float* __restrict__ y)
{
  const int tid = threadIdx.x;
  const int n  = tid & 15;
  const int ge = blockIdx.x * 16 + (tid >> 4);   // b*E + e
  const int b  = ge >> 12;                       // / E_
  const int e  = ge & (E_ - 1);
  const float Aen = -expf(A_log[e * N_ + n]);
  const float De  = Dvec[e];
  float state = 0.f;
  const int mbase = b * L_;
  for (int l = 0; l < L_; ++l) {
    const int m = mbase + l;
    const float dt = dts[(size_t)m * E_ + e];            // broadcast in group
    const float h  = hc[(size_t)m * E_ + e];             // broadcast
    const float Bm = ssm[(size_t)m * SLD + TR_ + n];     // per-lane
    const float Cm = ssm[(size_t)m * SLD + TR_ + N_ + n];
    state = fmaf(expf(dt * Aen), state, dt * Bm * h);
    float yp = state * Cm;
    yp += __shfl_xor(yp, 1);
    yp += __shfl_xor(yp, 2);
    yp += __shfl_xor(yp, 4);
    yp += __shfl_xor(yp, 8);
    const float g   = proj[(size_t)m * P2E + E_ + e];    // gate (broadcast)
    const float res = (yp + h * De) * siluf(g);
    if (n == 0) y[(size_t)m * E_ + e] = res;
  }
}

// ---------------------------------------------------------------------------
extern "C" void kernel_launch(void* const* d_in, const int* in_sizes, int n_in,
                              void* d_out, int out_size, void* d_ws, size_t ws_size,
                              hipStream_t stream)
{
  const float* x_in  = (const float*)d_in[0];
  const float* W_in  = (const float*)d_in[1];
  const float* ck    = (const float*)d_in[2];
  const float* cb    = (const float*)d_in[3];
  const float* W_x   = (const float*)d_in[4];
  const float* W_dt  = (const float*)d_in[5];
  const float* b_dt  = (const float*)d_in[6];
  const float* W_out = (const float*)d_in[7];
  const float* A_log = (const float*)d_in[8];
  const float* Dvec  = (const float*)d_in[9];
  float* out = (float*)d_out;
  float* ws  = (float*)d_ws;

  // workspace layout (floats)
  float* proj = ws;                               // M x 2E   (64 MB)
  float* hc   = proj + (size_t)M_ * P2E;          // M x E    (32 MB)
  float* dts  = hc   + (size_t)M_ * E_;           // M x E    (32 MB)
  float* ssm  = dts  + (size_t)M_ * E_;           // M x 160  (1.3 MB)
  // y: separate buffer if workspace allows (avoids dts/y alias serializing
  // the scan's load/store ordering); alias dts otherwise (still correct:
  // each location is read by its owning wave strictly before its write).
  size_t base_f = (size_t)M_ * P2E + 2 * (size_t)M_ * E_ + (size_t)M_ * SLD;
  size_t need   = (base_f + (size_t)M_ * E_) * sizeof(float);
  float* yb = (ws_size >= need) ? (ssm + (size_t)M_ * SLD) : dts;

  // x-proj accumulates with split-K atomics -> zero it every call
  hipMemsetAsync(ssm, 0, (size_t)M_ * SLD * sizeof(float), stream);

  // 1) proj = input @ W_in            (2048 x 8192, K=2048)
  sgemm_k<128,64,16,8,4,0><<<dim3(P2E/64, M_/128, 1), 256, 0, stream>>>(
      x_in, W_in, proj, H_, P2E, P2E, nullptr, H_);
  // 2) depthwise causal conv + SiLU   (hc[m,e])
  conv_silu_k<<<(M_ * E_) / 256, 256, 0, stream>>>(proj, ck, cb, hc);
  // 3) ssm = hc @ W_x                 (2048 x 160, K=4096, split-K=8, atomic)
  sgemm_k<64,32,16,4,2,2><<<dim3(SLD/32, M_/64, 8), 256, 0, stream>>>(
      hc, W_x, ssm, E_, SLD, SLD, nullptr, E_/8);
  // 4) dts = softplus(ssm[:, :128] @ W_dt + b_dt)   (2048 x 4096, K=128)
  sgemm_k<128,64,16,8,4,1><<<dim3(E_/64, M_/128, 1), 256, 0, stream>>>(
      ssm, W_dt, dts, SLD, E_, E_, b_dt, TR_);
  // 5) selective scan + D-skip + gate
  scan_k<<<(B_ * E_) / 16, 256, 0, stream>>>(hc, ssm, proj, A_log, Dvec, dts, yb);
  // 6) out = y @ W_out                (2048 x 2048, K=4096)
  sgemm_k<128,64,16,8,4,0><<<dim3(H_/64, M_/128, 1), 256, 0, stream>>>(
      yb, W_out, out, E_, H_, H_, nullptr, E_);
}

// Round 2
// 1506.318 us; speedup vs baseline: 1.6345x; 1.6345x over previous
//
#include <hip/hip_runtime.h>
#include <cstddef>
#include <cstdint>

// Problem constants (from reference): B,L,H,E,N,TR,K
constexpr int B_  = 2;
constexpr int L_  = 1024;
constexpr int H_  = 2048;
constexpr int E_  = 4096;
constexpr int N_  = 16;
constexpr int TR_ = 128;
constexpr int M_  = B_ * L_;        // 2048 token rows
constexpr int P2E = 2 * E_;         // 8192  (proj leading dim)
constexpr int SLD = TR_ + 2 * N_;   // 160   (ssm_p leading dim)

typedef unsigned short u16;
using short8 = __attribute__((ext_vector_type(8))) short;
using f32x4  = __attribute__((ext_vector_type(4))) float;

__device__ __forceinline__ float siluf(float x) { return x / (1.f + expf(-x)); }
__device__ __forceinline__ float softplusf(float x) {
  return fmaxf(x, 0.f) + log1pf(expf(-fabsf(x)));
}
__device__ __forceinline__ u16 f2bf(float x) {
  union { float f; uint32_t u; } v; v.f = x;
  uint32_t r = v.u + 0x7FFFu + ((v.u >> 16) & 1u);   // RNE
  return (u16)(r >> 16);
}
__device__ __forceinline__ float bf2f(u16 h) {
  union { uint32_t u; float f; } v; v.u = ((uint32_t)h) << 16; return v.f;
}

// ---------------------------------------------------------------------------
// fp32 tiled GEMM (kept for x-proj, dt-proj, and as full-pipeline fallback)
// ---------------------------------------------------------------------------
template<int BM, int BN, int BK, int TM, int TN, int EPI>
__global__ __launch_bounds__(256) void sgemm_k(
    const float* __restrict__ A, const float* __restrict__ B,
    float* __restrict__ C, int lda, int ldb, int ldc,
    const float* __restrict__ bias, int kchunk)
{
  __shared__ float As[BK][BM + 4];
  __shared__ float Bs[BK][BN];
  const int tid = threadIdx.x;
  const int tx  = tid & 15;
  const int ty  = tid >> 4;
  const int m0  = blockIdx.y * BM;
  const int n0  = blockIdx.x * BN;
  const int k00 = blockIdx.z * kchunk;

  float acc[TM][TN];
#pragma unroll
  for (int i = 0; i < TM; ++i)
#pragma unroll
    for (int j = 0; j < TN; ++j) acc[i][j] = 0.f;

  for (int k0 = k00; k0 < k00 + kchunk; k0 += BK) {
    constexpr int A4 = BM * BK / 4;
#pragma unroll
    for (int it = 0; it < (A4 + 255) / 256; ++it) {
      int i = it * 256 + tid;
      if ((A4 % 256 == 0) || (i < A4)) {
        int row = i / (BK / 4);
        int kc  = (i % (BK / 4)) * 4;
        float4 v = *reinterpret_cast<const float4*>(
            A + (size_t)(m0 + row) * lda + k0 + kc);
        As[kc + 0][row] = v.x; As[kc + 1][row] = v.y;
        As[kc + 2][row] = v.z; As[kc + 3][row] = v.w;
      }
    }
    constexpr int B4 = BK * BN / 4;
#pragma unroll
    for (int it = 0; it < (B4 + 255) / 256; ++it) {
      int i = it * 256 + tid;
      if ((B4 % 256 == 0) || (i < B4)) {
        int kr = i / (BN / 4);
        int nc = (i % (BN / 4)) * 4;
        *reinterpret_cast<float4*>(&Bs[kr][nc]) =
            *reinterpret_cast<const float4*>(
                B + (size_t)(k0 + kr) * ldb + n0 + nc);
      }
    }
    __syncthreads();
#pragma unroll
    for (int k = 0; k < BK; ++k) {
      float a[TM], bb[TN];
      const float* ap = &As[k][ty * TM];
      if constexpr (TM == 8) {
        float4 a0 = *reinterpret_cast<const float4*>(ap);
        float4 a1 = *reinterpret_cast<const float4*>(ap + 4);
        a[0]=a0.x; a[1]=a0.y; a[2]=a0.z; a[3]=a0.w;
        a[4]=a1.x; a[5]=a1.y; a[6]=a1.z; a[7]=a1.w;
      } else {
        float4 a0 = *reinterpret_cast<const float4*>(ap);
        a[0]=a0.x; a[1]=a0.y; a[2]=a0.z; a[3]=a0.w;
      }
      const float* bp = &Bs[k][tx * TN];
      if constexpr (TN == 4) {
        float4 b0 = *reinterpret_cast<const float4*>(bp);
        bb[0]=b0.x; bb[1]=b0.y; bb[2]=b0.z; bb[3]=b0.w;
      } else {
        float2 b0 = *reinterpret_cast<const float2*>(bp);
        bb[0]=b0.x; bb[1]=b0.y;
      }
#pragma unroll
      for (int i = 0; i < TM; ++i)
#pragma unroll
        for (int j = 0; j < TN; ++j) acc[i][j] = fmaf(a[i], bb[j], acc[i][j]);
    }
    __syncthreads();
  }

#pragma unroll
  for (int i = 0; i < TM; ++i) {
    int row = m0 + ty * TM + i;
    float* crow = C + (size_t)row * ldc + n0 + tx * TN;
    if constexpr (EPI == 2) {
#pragma unroll
      for (int j = 0; j < TN; ++j) atomicAdd(&crow[j], acc[i][j]);
    } else if constexpr (EPI == 1) {
      const float* brow = bias + n0 + tx * TN;
      float4 v;
      v.x = softplusf(acc[i][0] + brow[0]);
      v.y = softplusf(acc[i][1] + brow[1]);
      v.z = softplusf(acc[i][2] + brow[2]);
      v.w = softplusf(acc[i][3] + brow[3]);
      *reinterpret_cast<float4*>(crow) = v;
    } else {
      if constexpr (TN == 4) {
        float4 v; v.x=acc[i][0]; v.y=acc[i][1]; v.z=acc[i][2]; v.w=acc[i][3];
        *reinterpret_cast<float4*>(crow) = v;
      } else {
#pragma unroll
        for (int j = 0; j < TN; ++j) crow[j] = acc[i][j];
      }
    }
  }
}

// ---------------------------------------------------------------------------
// fp32 -> (bf16 hi, bf16 lo), row-major passthrough. 4 floats / thread.
// ---------------------------------------------------------------------------
__global__ __launch_bounds__(256) void decomp_k(
    const float* __restrict__ in, u16* __restrict__ hi, u16* __restrict__ lo,
    int n4)
{
  int i = blockIdx.x * 256 + threadIdx.x;
  if (i >= n4) return;
  float4 v = *reinterpret_cast<const float4*>(in + (size_t)i * 4);
  u16 h[4], l[4];
  float x[4] = {v.x, v.y, v.z, v.w};
#pragma unroll
  for (int j = 0; j < 4; ++j) {
    h[j] = f2bf(x[j]);
    l[j] = f2bf(x[j] - bf2f(h[j]));
  }
  uint32_t h0 = h[0] | ((uint32_t)h[1] << 16), h1 = h[2] | ((uint32_t)h[3] << 16);
  uint32_t l0 = l[0] | ((uint32_t)l[1] << 16), l1 = l[2] | ((uint32_t)l[3] << 16);
  *reinterpret_cast<uint2*>(hi + (size_t)i * 4) = make_uint2(h0, h1);
  *reinterpret_cast<uint2*>(lo + (size_t)i * 4) = make_uint2(l0, l1);
}

// ---------------------------------------------------------------------------
// W[KD][ND] fp32 -> Wt_hi/Wt_lo [ND][KD] bf16 (transpose + decompose).
// 64x64 tiles via LDS, 256 threads.
// ---------------------------------------------------------------------------
__global__ __launch_bounds__(256) void wdecomp_t_k(
    const float* __restrict__ W, u16* __restrict__ Whi, u16* __restrict__ Wlo,
    int KD, int ND)
{
  __shared__ float T[64][69];
  const int t  = threadIdx.x;
  const int n0 = blockIdx.x * 64;
  const int k0 = blockIdx.y * 64;
#pragma unroll
  for (int it = 0; it < 4; ++it) {
    int f  = it * 256 + t;
    int kk = f >> 4;
    int c  = (f & 15) * 4;
    float4 v = *reinterpret_cast<const float4*>(
        W + (size_t)(k0 + kk) * ND + n0 + c);
    T[kk][c] = v.x; T[kk][c+1] = v.y; T[kk][c+2] = v.z; T[kk][c+3] = v.w;
  }
  __syncthreads();
  const int nn   = t >> 2;
  const int kseg = (t & 3) * 16;
  const size_t off = (size_t)(n0 + nn) * KD + k0 + kseg;
#pragma unroll
  for (int half = 0; half < 2; ++half) {
    uint32_t hp[4], lp[4];
#pragma unroll
    for (int jj = 0; jj < 4; ++jj) {
      float x0 = T[kseg + half * 8 + jj * 2 + 0][nn];
      float x1 = T[kseg + half * 8 + jj * 2 + 1][nn];
      u16 h0 = f2bf(x0), h1 = f2bf(x1);
      u16 l0 = f2bf(x0 - bf2f(h0)), l1 = f2bf(x1 - bf2f(h1));
      hp[jj] = h0 | ((uint32_t)h1 << 16);
      lp[jj] = l0 | ((uint32_t)l1 << 16);
    }
    *reinterpret_cast<uint4*>(Whi + off + half * 8) =
        make_uint4(hp[0], hp[1], hp[2], hp[3]);
    *reinterpret_cast<uint4*>(Wlo + off + half * 8) =
        make_uint4(lp[0], lp[1], lp[2], lp[3]);
  }
}

// ---------------------------------------------------------------------------
// Split-bf16 MFMA GEMM: C[M][N] fp32 = A[M][K] x Bt[N][K]^T via
//   Ah*Bh + Ah*Bl + Al*Bh (3x mfma_f32_16x16x32_bf16, fp32 accumulate).
// 128x128 tile, BK=32, 4 waves (2x2), each wave 64x64 = 4x4 fragments.
// ---------------------------------------------------------------------------
__global__ __launch_bounds__(256) void gemm3bf_k(
    const u16* __restrict__ Ah, const u16* __restrict__ Al,
    const u16* __restrict__ Bh, const u16* __restrict__ Bl,
    float* __restrict__ C, int K, int ldc)
{
  constexpr int BK  = 32;
  constexpr int LDK = BK + 8;   // 40 u16 = 80 B rows: 2-way bank aliasing (free)
  __shared__ __align__(16) u16 sAh[128 * LDK];
  __shared__ __align__(16) u16 sAl[128 * LDK];
  __shared__ __align__(16) u16 sBh[128 * LDK];
  __shared__ __align__(16) u16 sBl[128 * LDK];

  const int tid  = threadIdx.x;
  const int lane = tid & 63;
  const int wid  = tid >> 6;
  const int wr   = wid >> 1, wc = wid & 1;
  const int m0   = blockIdx.y * 128;
  const int n0   = blockIdx.x * 128;

  // staging: 512 x 16B chunks per tile; thread covers rows r0 and r0+64, col c0
  const int r0 = tid >> 2;
  const int c0 = (tid & 3) * 8;

  const u16* gAh0 = Ah + (size_t)(m0 + r0) * K + c0;
  const u16* gAh1 = Ah + (size_t)(m0 + r0 + 64) * K + c0;
  const u16* gAl0 = Al + (size_t)(m0 + r0) * K + c0;
  const u16* gAl1 = Al + (size_t)(m0 + r0 + 64) * K + c0;
  const u16* gBh0 = Bh + (size_t)(n0 + r0) * K + c0;
  const u16* gBh1 = Bh + (size_t)(n0 + r0 + 64) * K + c0;
  const u16* gBl0 = Bl + (size_t)(n0 + r0) * K + c0;
  const u16* gBl1 = Bl + (size_t)(n0 + r0 + 64) * K + c0;

  const int s0 = r0 * LDK + c0;
  const int s1 = (r0 + 64) * LDK + c0;

  f32x4 acc[4][4] = {};

  const int fr = lane & 15;          // fragment row/col within 16
  const int fk = (lane >> 4) * 8;    // k-offset of this lane's 8 elements

  for (int k0 = 0; k0 < K; k0 += BK) {
    uint4 vah0 = *reinterpret_cast<const uint4*>(gAh0 + k0);
    uint4 vah1 = *reinterpret_cast<const uint4*>(gAh1 + k0);
    uint4 val0 = *reinterpret_cast<const uint4*>(gAl0 + k0);
    uint4 val1 = *reinterpret_cast<const uint4*>(gAl1 + k0);
    uint4 vbh0 = *reinterpret_cast<const uint4*>(gBh0 + k0);
    uint4 vbh1 = *reinterpret_cast<const uint4*>(gBh1 + k0);
    uint4 vbl0 = *reinterpret_cast<const uint4*>(gBl0 + k0);
    uint4 vbl1 = *reinterpret_cast<const uint4*>(gBl1 + k0);
    __syncthreads();   // previous iteration's LDS reads complete
    *reinterpret_cast<uint4*>(&sAh[s0]) = vah0;
    *reinterpret_cast<uint4*>(&sAh[s1]) = vah1;
    *reinterpret_cast<uint4*>(&sAl[s0]) = val0;
    *reinterpret_cast<uint4*>(&sAl[s1]) = val1;
    *reinterpret_cast<uint4*>(&sBh[s0]) = vbh0;
    *reinterpret_cast<uint4*>(&sBh[s1]) = vbh1;
    *reinterpret_cast<uint4*>(&sBl[s0]) = vbl0;
    *reinterpret_cast<uint4*>(&sBl[s1]) = vbl1;
    __syncthreads();

    short8 bhf[4], blf[4];
#pragma unroll
    for (int nc = 0; nc < 4; ++nc) {
      int row = wc * 64 + nc * 16 + fr;
      bhf[nc] = *reinterpret_cast<const short8*>(&sBh[row * LDK + fk]);
      blf[nc] = *reinterpret_cast<const short8*>(&sBl[row * LDK + fk]);
    }
#pragma unroll
    for (int mr = 0; mr < 4; ++mr) {
      int row = wr * 64 + mr * 16 + fr;
      short8 ahf = *reinterpret_cast<const short8*>(&sAh[row * LDK + fk]);
      short8 alf = *reinterpret_cast<const short8*>(&sAl[row * LDK + fk]);
#pragma unroll
      for (int nc = 0; nc < 4; ++nc) {
        acc[mr][nc] = __builtin_amdgcn_mfma_f32_16x16x32_bf16(ahf, bhf[nc], acc[mr][nc], 0, 0, 0);
        acc[mr][nc] = __builtin_amdgcn_mfma_f32_16x16x32_bf16(ahf, blf[nc], acc[mr][nc], 0, 0, 0);
        acc[mr][nc] = __builtin_amdgcn_mfma_f32_16x16x32_bf16(alf, bhf[nc], acc[mr][nc], 0, 0, 0);
      }
    }
  }

  // epilogue: C/D layout col=lane&15, row=(lane>>4)*4+i   [m89-verified]
#pragma unroll
  for (int mr = 0; mr < 4; ++mr) {
    const int rowb = m0 + wr * 64 + mr * 16 + ((lane >> 4) << 2);
#pragma unroll
    for (int nc = 0; nc < 4; ++nc) {
      const int col = n0 + wc * 64 + nc * 16 + fr;
      float* cp = C + (size_t)rowb * ldc + col;
#pragma unroll
      for (int i = 0; i < 4; ++i) cp[(size_t)i * ldc] = acc[mr][nc][i];
    }
  }
}

// ---------------------------------------------------------------------------
// Depthwise causal conv1d (K=4) + bias + SiLU
// ---------------------------------------------------------------------------
__global__ __launch_bounds__(256) void conv_silu_k(
    const float* __restrict__ proj, const float* __restrict__ ck,
    const float* __restrict__ cb, float* __restrict__ hc)
{
  const int idx = blockIdx.x * 256 + threadIdx.x;
  const int e = idx & (E_ - 1);
  const int m = idx >> 12;
  const int l = m & (L_ - 1);
  const float c0 = ck[e * 4 + 0], c1 = ck[e * 4 + 1];
  const float c2 = ck[e * 4 + 2], c3 = ck[e * 4 + 3];
  const float* pcol = proj + (size_t)m * P2E + e;
  float acc = cb[e];
  if (l >= 3) acc = fmaf(pcol[-3 * P2E], c0, acc);
  if (l >= 2) acc = fmaf(pcol[-2 * P2E], c1, acc);
  if (l >= 1) acc = fmaf(pcol[-1 * P2E], c2, acc);
  acc = fmaf(pcol[0], c3, acc);
  hc[(size_t)m * E_ + e] = siluf(acc);
}

// ---------------------------------------------------------------------------
// Selective scan + D-skip + gate.  BF: write y as bf16 hi/lo, else fp32.
// ---------------------------------------------------------------------------
template<bool BF>
__global__ __launch_bounds__(256) void scan_k(
    const float* __restrict__ hc, const float* __restrict__ ssm,
    const float* __restrict__ proj, const float* __restrict__ A_log,
    const float* __restrict__ Dvec, const float* __restrict__ dts,
    float* __restrict__ yf, u16* __restrict__ yhi, u16* __restrict__ ylo)
{
  const int tid = threadIdx.x;
  const int n  = tid & 15;
  const int ge = blockIdx.x * 16 + (tid >> 4);
  const int b  = ge >> 12;
  const int e  = ge & (E_ - 1);
  const float Aen = -expf(A_log[e * N_ + n]);
  const float De  = Dvec[e];
  float state = 0.f;
  const int mbase = b * L_;
  for (int l = 0; l < L_; ++l) {
    const int m = mbase + l;
    const float dt = dts[(size_t)m * E_ + e];
    const float h  = hc[(size_t)m * E_ + e];
    const float Bm = ssm[(size_t)m * SLD + TR_ + n];
    const float Cm = ssm[(size_t)m * SLD + TR_ + N_ + n];
    state = fmaf(expf(dt * Aen), state, dt * Bm * h);
    float yp = state * Cm;
    yp += __shfl_xor(yp, 1);
    yp += __shfl_xor(yp, 2);
    yp += __shfl_xor(yp, 4);
    yp += __shfl_xor(yp, 8);
    const float g   = proj[(size_t)m * P2E + E_ + e];
    const float res = (yp + h * De) * siluf(g);
    if (n == 0) {
      if constexpr (BF) {
        u16 hv = f2bf(res);
        yhi[(size_t)m * E_ + e] = hv;
        ylo[(size_t)m * E_ + e] = f2bf(res - bf2f(hv));
      } else {
        yf[(size_t)m * E_ + e] = res;
      }
    }
  }
}

// ---------------------------------------------------------------------------
extern "C" void kernel_launch(void* const* d_in, const int* in_sizes, int n_in,
                              void* d_out, int out_size, void* d_ws, size_t ws_size,
                              hipStream_t stream)
{
  const float* x_in  = (const float*)d_in[0];
  const float* W_in  = (const float*)d_in[1];
  const float* ck    = (const float*)d_in[2];
  const float* cb    = (const float*)d_in[3];
  const float* W_x   = (const float*)d_in[4];
  const float* W_dt  = (const float*)d_in[5];
  const float* b_dt  = (const float*)d_in[6];
  const float* W_out = (const float*)d_in[7];
  const float* A_log = (const float*)d_in[8];
  const float* Dvec  = (const float*)d_in[9];
  float* out = (float*)d_out;
  float* ws  = (float*)d_ws;

  // common fp32 workspace
  float* proj = ws;                               // 16,777,216 f (64 MB)
  float* hc   = proj + (size_t)M_ * P2E;          // 8,388,608  f (32 MB)
  float* dts  = hc   + (size_t)M_ * E_;           // 8,388,608  f (32 MB)
  float* ssm  = dts  + (size_t)M_ * E_;           // 327,680    f (1.25 MB)

  // bf16 regions (new path), with lifetime-based aliasing:
  //  regA (32 MB): x_hi/x_lo (dead after in-proj)  -> Wo_hi/Wo_lo
  //  regB (64 MB): Wi_hi/Wi_lo (dead after in-proj) -> y_hi/y_lo
  u16* regA  = (u16*)(ssm + (size_t)M_ * SLD);
  u16* x_hi  = regA;
  u16* x_lo  = regA + (size_t)M_ * H_;            // +4,194,304
  u16* Wo_hi = regA;
  u16* Wo_lo = regA + (size_t)H_ * E_;            // +8,388,608
  u16* regB  = regA + 16777216;
  u16* Wi_hi = regB;
  u16* Wi_lo = regB + (size_t)P2E * H_;           // +16,777,216
  u16* y_hi  = regB;
  u16* y_lo  = regB + (size_t)M_ * E_;            // +8,388,608

  const size_t need_bf =
      ((size_t)M_ * P2E + 2 * (size_t)M_ * E_ + (size_t)M_ * SLD) * 4 +
      (16777216ULL + 33554432ULL) * 2;            // = 236,191,744 B

  // x-proj accumulates with split-K atomics -> zero it every call
  hipMemsetAsync(ssm, 0, (size_t)M_ * SLD * sizeof(float), stream);

  if (ws_size >= need_bf) {
    // ---- split-bf16 MFMA path ----
    // decompose input and transpose+decompose W_in
    decomp_k<<<(M_ * H_ / 4 + 255) / 256, 256, 0, stream>>>(
        x_in, x_hi, x_lo, M_ * H_ / 4);
    wdecomp_t_k<<<dim3(P2E / 64, H_ / 64), 256, 0, stream>>>(
        W_in, Wi_hi, Wi_lo, H_, P2E);
    // 1) proj = x @ W_in   (M x 8192, K=2048)
    gemm3bf_k<<<dim3(P2E / 128, M_ / 128), 256, 0, stream>>>(
        x_hi, x_lo, Wi_hi, Wi_lo, proj, H_, P2E);
    // 2) conv + SiLU
    conv_silu_k<<<(M_ * E_) / 256, 256, 0, stream>>>(proj, ck, cb, hc);
    // 3) ssm = hc @ W_x    (split-K=8, atomic)
    sgemm_k<64,32,16,4,2,2><<<dim3(SLD/32, M_/64, 8), 256, 0, stream>>>(
        hc, W_x, ssm, E_, SLD, SLD, nullptr, E_/8);
    // 4) dts = softplus(ssm[:, :128] @ W_dt + b_dt)
    sgemm_k<128,64,16,8,4,1><<<dim3(E_/64, M_/128, 1), 256, 0, stream>>>(
        ssm, W_dt, dts, SLD, E_, E_, b_dt, TR_);
    // transpose+decompose W_out (overwrites x_hi/x_lo region; x is dead)
    wdecomp_t_k<<<dim3(H_ / 64, E_ / 64), 256, 0, stream>>>(
        W_out, Wo_hi, Wo_lo, E_, H_);
    // 5) scan -> y hi/lo (overwrites Wi region; Wi is dead)
    scan_k<true><<<(B_ * E_) / 16, 256, 0, stream>>>(
        hc, ssm, proj, A_log, Dvec, dts, nullptr, y_hi, y_lo);
    // 6) out = y @ W_out   (M x 2048, K=4096)
    gemm3bf_k<<<dim3(H_ / 128, M_ / 128), 256, 0, stream>>>(
        y_hi, y_lo, Wo_hi, Wo_lo, out, E_, H_);
  } else {
    // ---- fp32 fallback (round-1 pipeline) ----
    size_t base_f = (size_t)M_ * P2E + 2 * (size_t)M_ * E_ + (size_t)M_ * SLD;
    size_t need   = (base_f + (size_t)M_ * E_) * sizeof(float);
    float* yb = (ws_size >= need) ? (ssm + (size_t)M_ * SLD) : dts;
    sgemm_k<128,64,16,8,4,0><<<dim3(P2E/64, M_/128, 1), 256, 0, stream>>>(
        x_in, W_in, proj, H_, P2E, P2E, nullptr, H_);
    conv_silu_k<<<(M_ * E_) / 256, 256, 0, stream>>>(proj, ck, cb, hc);
    sgemm_k<64,32,16,4,2,2><<<dim3(SLD/32, M_/64, 8), 256, 0, stream>>>(
        hc, W_x, ssm, E_, SLD, SLD, nullptr, E_/8);
    sgemm_k<128,64,16,8,4,1><<<dim3(E_/64, M_/128, 1), 256, 0, stream>>>(
        ssm, W_dt, dts, SLD, E_, E_, b_dt, TR_);
    scan_k<false><<<(B_ * E_) / 16, 256, 0, stream>>>(
        hc, ssm, proj, A_log, Dvec, dts, yb, nullptr, nullptr);
    sgemm_k<128,64,16,8,4,0><<<dim3(H_/64, M_/128, 1), 256, 0, stream>>>(
        yb, W_out, out, E_, H_, H_, nullptr, E_);
  }
}

// Round 3
// 1042.123 us; speedup vs baseline: 2.3626x; 1.4454x over previous
//
#include <hip/hip_runtime.h>
#include <cstddef>
#include <cstdint>

// Problem constants (from reference): B,L,H,E,N,TR,K
constexpr int B_  = 2;
constexpr int L_  = 1024;
constexpr int H_  = 2048;
constexpr int E_  = 4096;
constexpr int N_  = 16;
constexpr int TR_ = 128;
constexpr int M_  = B_ * L_;        // 2048 token rows
constexpr int P2E = 2 * E_;         // 8192  (proj leading dim)
constexpr int SLD = TR_ + 2 * N_;   // 160   (ssm_p leading dim)
constexpr int CH_ = 16;             // scan chunks along L
constexpr int CL_ = L_ / CH_;       // 64 steps per chunk

typedef unsigned short u16;
using short8 = __attribute__((ext_vector_type(8))) short;
using f32x4  = __attribute__((ext_vector_type(4))) float;

__device__ __forceinline__ float siluf(float x) { return x / (1.f + expf(-x)); }
__device__ __forceinline__ float softplusf(float x) {
  return fmaxf(x, 0.f) + log1pf(expf(-fabsf(x)));
}
__device__ __forceinline__ u16 f2bf(float x) {
  union { float f; uint32_t u; } v; v.f = x;
  uint32_t r = v.u + 0x7FFFu + ((v.u >> 16) & 1u);   // RNE
  return (u16)(r >> 16);
}
__device__ __forceinline__ float bf2f(u16 h) {
  union { uint32_t u; float f; } v; v.u = ((uint32_t)h) << 16; return v.f;
}

// ---------------------------------------------------------------------------
// fp32 tiled GEMM (x-proj, dt-proj, and full-pipeline fallback)
// ---------------------------------------------------------------------------
template<int BM, int BN, int BK, int TM, int TN, int EPI>
__global__ __launch_bounds__(256) void sgemm_k(
    const float* __restrict__ A, const float* __restrict__ B,
    float* __restrict__ C, int lda, int ldb, int ldc,
    const float* __restrict__ bias, int kchunk)
{
  __shared__ float As[BK][BM + 4];
  __shared__ float Bs[BK][BN];
  const int tid = threadIdx.x;
  const int tx  = tid & 15;
  const int ty  = tid >> 4;
  const int m0  = blockIdx.y * BM;
  const int n0  = blockIdx.x * BN;
  const int k00 = blockIdx.z * kchunk;

  float acc[TM][TN];
#pragma unroll
  for (int i = 0; i < TM; ++i)
#pragma unroll
    for (int j = 0; j < TN; ++j) acc[i][j] = 0.f;

  for (int k0 = k00; k0 < k00 + kchunk; k0 += BK) {
    constexpr int A4 = BM * BK / 4;
#pragma unroll
    for (int it = 0; it < (A4 + 255) / 256; ++it) {
      int i = it * 256 + tid;
      if ((A4 % 256 == 0) || (i < A4)) {
        int row = i / (BK / 4);
        int kc  = (i % (BK / 4)) * 4;
        float4 v = *reinterpret_cast<const float4*>(
            A + (size_t)(m0 + row) * lda + k0 + kc);
        As[kc + 0][row] = v.x; As[kc + 1][row] = v.y;
        As[kc + 2][row] = v.z; As[kc + 3][row] = v.w;
      }
    }
    constexpr int B4 = BK * BN / 4;
#pragma unroll
    for (int it = 0; it < (B4 + 255) / 256; ++it) {
      int i = it * 256 + tid;
      if ((B4 % 256 == 0) || (i < B4)) {
        int kr = i / (BN / 4);
        int nc = (i % (BN / 4)) * 4;
        *reinterpret_cast<float4*>(&Bs[kr][nc]) =
            *reinterpret_cast<const float4*>(
                B + (size_t)(k0 + kr) * ldb + n0 + nc);
      }
    }
    __syncthreads();
#pragma unroll
    for (int k = 0; k < BK; ++k) {
      float a[TM], bb[TN];
      const float* ap = &As[k][ty * TM];
      if constexpr (TM == 8) {
        float4 a0 = *reinterpret_cast<const float4*>(ap);
        float4 a1 = *reinterpret_cast<const float4*>(ap + 4);
        a[0]=a0.x; a[1]=a0.y; a[2]=a0.z; a[3]=a0.w;
        a[4]=a1.x; a[5]=a1.y; a[6]=a1.z; a[7]=a1.w;
      } else {
        float4 a0 = *reinterpret_cast<const float4*>(ap);
        a[0]=a0.x; a[1]=a0.y; a[2]=a0.z; a[3]=a0.w;
      }
      const float* bp = &Bs[k][tx * TN];
      if constexpr (TN == 4) {
        float4 b0 = *reinterpret_cast<const float4*>(bp);
        bb[0]=b0.x; bb[1]=b0.y; bb[2]=b0.z; bb[3]=b0.w;
      } else {
        float2 b0 = *reinterpret_cast<const float2*>(bp);
        bb[0]=b0.x; bb[1]=b0.y;
      }
#pragma unroll
      for (int i = 0; i < TM; ++i)
#pragma unroll
        for (int j = 0; j < TN; ++j) acc[i][j] = fmaf(a[i], bb[j], acc[i][j]);
    }
    __syncthreads();
  }

#pragma unroll
  for (int i = 0; i < TM; ++i) {
    int row = m0 + ty * TM + i;
    float* crow = C + (size_t)row * ldc + n0 + tx * TN;
    if constexpr (EPI == 2) {
#pragma unroll
      for (int j = 0; j < TN; ++j) atomicAdd(&crow[j], acc[i][j]);
    } else if constexpr (EPI == 1) {
      const float* brow = bias + n0 + tx * TN;
      float4 v;
      v.x = softplusf(acc[i][0] + brow[0]);
      v.y = softplusf(acc[i][1] + brow[1]);
      v.z = softplusf(acc[i][2] + brow[2]);
      v.w = softplusf(acc[i][3] + brow[3]);
      *reinterpret_cast<float4*>(crow) = v;
    } else {
      if constexpr (TN == 4) {
        float4 v; v.x=acc[i][0]; v.y=acc[i][1]; v.z=acc[i][2]; v.w=acc[i][3];
        *reinterpret_cast<float4*>(crow) = v;
      } else {
#pragma unroll
        for (int j = 0; j < TN; ++j) crow[j] = acc[i][j];
      }
    }
  }
}

// ---------------------------------------------------------------------------
// fp32 -> (bf16 hi, bf16 lo), row-major passthrough. 4 floats / thread.
// ---------------------------------------------------------------------------
__global__ __launch_bounds__(256) void decomp_k(
    const float* __restrict__ in, u16* __restrict__ hi, u16* __restrict__ lo,
    int n4)
{
  int i = blockIdx.x * 256 + threadIdx.x;
  if (i >= n4) return;
  float4 v = *reinterpret_cast<const float4*>(in + (size_t)i * 4);
  u16 h[4], l[4];
  float x[4] = {v.x, v.y, v.z, v.w};
#pragma unroll
  for (int j = 0; j < 4; ++j) {
    h[j] = f2bf(x[j]);
    l[j] = f2bf(x[j] - bf2f(h[j]));
  }
  uint32_t h0 = h[0] | ((uint32_t)h[1] << 16), h1 = h[2] | ((uint32_t)h[3] << 16);
  uint32_t l0 = l[0] | ((uint32_t)l[1] << 16), l1 = l[2] | ((uint32_t)l[3] << 16);
  *reinterpret_cast<uint2*>(hi + (size_t)i * 4) = make_uint2(h0, h1);
  *reinterpret_cast<uint2*>(lo + (size_t)i * 4) = make_uint2(l0, l1);
}

// ---------------------------------------------------------------------------
// W[KD][ND] fp32 -> Wt_hi/Wt_lo [ND][KD] bf16 (transpose + decompose).
// ---------------------------------------------------------------------------
__global__ __launch_bounds__(256) void wdecomp_t_k(
    const float* __restrict__ W, u16* __restrict__ Whi, u16* __restrict__ Wlo,
    int KD, int ND)
{
  __shared__ float T[64][69];
  const int t  = threadIdx.x;
  const int n0 = blockIdx.x * 64;
  const int k0 = blockIdx.y * 64;
#pragma unroll
  for (int it = 0; it < 4; ++it) {
    int f  = it * 256 + t;
    int kk = f >> 4;
    int c  = (f & 15) * 4;
    float4 v = *reinterpret_cast<const float4*>(
        W + (size_t)(k0 + kk) * ND + n0 + c);
    T[kk][c] = v.x; T[kk][c+1] = v.y; T[kk][c+2] = v.z; T[kk][c+3] = v.w;
  }
  __syncthreads();
  const int nn   = t >> 2;
  const int kseg = (t & 3) * 16;
  const size_t off = (size_t)(n0 + nn) * KD + k0 + kseg;
#pragma unroll
  for (int half = 0; half < 2; ++half) {
    uint32_t hp[4], lp[4];
#pragma unroll
    for (int jj = 0; jj < 4; ++jj) {
      float x0 = T[kseg + half * 8 + jj * 2 + 0][nn];
      float x1 = T[kseg + half * 8 + jj * 2 + 1][nn];
      u16 h0 = f2bf(x0), h1 = f2bf(x1);
      u16 l0 = f2bf(x0 - bf2f(h0)), l1 = f2bf(x1 - bf2f(h1));
      hp[jj] = h0 | ((uint32_t)h1 << 16);
      lp[jj] = l0 | ((uint32_t)l1 << 16);
    }
    *reinterpret_cast<uint4*>(Whi + off + half * 8) =
        make_uint4(hp[0], hp[1], hp[2], hp[3]);
    *reinterpret_cast<uint4*>(Wlo + off + half * 8) =
        make_uint4(lp[0], lp[1], lp[2], lp[3]);
  }
}

// ---------------------------------------------------------------------------
// Split-bf16 MFMA GEMM: C[M][N] fp32 = A[M][K] x Bt[N][K]^T via
//   Ah*Bh + Ah*Bl + Al*Bh (3x mfma_f32_16x16x32_bf16, fp32 accumulate).
// ---------------------------------------------------------------------------
__global__ __launch_bounds__(256) void gemm3bf_k(
    const u16* __restrict__ Ah, const u16* __restrict__ Al,
    const u16* __restrict__ Bh, const u16* __restrict__ Bl,
    float* __restrict__ C, int K, int ldc)
{
  constexpr int BK  = 32;
  constexpr int LDK = BK + 8;
  __shared__ __align__(16) u16 sAh[128 * LDK];
  __shared__ __align__(16) u16 sAl[128 * LDK];
  __shared__ __align__(16) u16 sBh[128 * LDK];
  __shared__ __align__(16) u16 sBl[128 * LDK];

  const int tid  = threadIdx.x;
  const int lane = tid & 63;
  const int wid  = tid >> 6;
  const int wr   = wid >> 1, wc = wid & 1;
  const int m0   = blockIdx.y * 128;
  const int n0   = blockIdx.x * 128;

  const int r0 = tid >> 2;
  const int c0 = (tid & 3) * 8;

  const u16* gAh0 = Ah + (size_t)(m0 + r0) * K + c0;
  const u16* gAh1 = Ah + (size_t)(m0 + r0 + 64) * K + c0;
  const u16* gAl0 = Al + (size_t)(m0 + r0) * K + c0;
  const u16* gAl1 = Al + (size_t)(m0 + r0 + 64) * K + c0;
  const u16* gBh0 = Bh + (size_t)(n0 + r0) * K + c0;
  const u16* gBh1 = Bh + (size_t)(n0 + r0 + 64) * K + c0;
  const u16* gBl0 = Bl + (size_t)(n0 + r0) * K + c0;
  const u16* gBl1 = Bl + (size_t)(n0 + r0 + 64) * K + c0;

  const int s0 = r0 * LDK + c0;
  const int s1 = (r0 + 64) * LDK + c0;

  f32x4 acc[4][4] = {};

  const int fr = lane & 15;
  const int fk = (lane >> 4) * 8;

  for (int k0 = 0; k0 < K; k0 += BK) {
    uint4 vah0 = *reinterpret_cast<const uint4*>(gAh0 + k0);
    uint4 vah1 = *reinterpret_cast<const uint4*>(gAh1 + k0);
    uint4 val0 = *reinterpret_cast<const uint4*>(gAl0 + k0);
    uint4 val1 = *reinterpret_cast<const uint4*>(gAl1 + k0);
    uint4 vbh0 = *reinterpret_cast<const uint4*>(gBh0 + k0);
    uint4 vbh1 = *reinterpret_cast<const uint4*>(gBh1 + k0);
    uint4 vbl0 = *reinterpret_cast<const uint4*>(gBl0 + k0);
    uint4 vbl1 = *reinterpret_cast<const uint4*>(gBl1 + k0);
    __syncthreads();
    *reinterpret_cast<uint4*>(&sAh[s0]) = vah0;
    *reinterpret_cast<uint4*>(&sAh[s1]) = vah1;
    *reinterpret_cast<uint4*>(&sAl[s0]) = val0;
    *reinterpret_cast<uint4*>(&sAl[s1]) = val1;
    *reinterpret_cast<uint4*>(&sBh[s0]) = vbh0;
    *reinterpret_cast<uint4*>(&sBh[s1]) = vbh1;
    *reinterpret_cast<uint4*>(&sBl[s0]) = vbl0;
    *reinterpret_cast<uint4*>(&sBl[s1]) = vbl1;
    __syncthreads();

    short8 bhf[4], blf[4];
#pragma unroll
    for (int nc = 0; nc < 4; ++nc) {
      int row = wc * 64 + nc * 16 + fr;
      bhf[nc] = *reinterpret_cast<const short8*>(&sBh[row * LDK + fk]);
      blf[nc] = *reinterpret_cast<const short8*>(&sBl[row * LDK + fk]);
    }
#pragma unroll
    for (int mr = 0; mr < 4; ++mr) {
      int row = wr * 64 + mr * 16 + fr;
      short8 ahf = *reinterpret_cast<const short8*>(&sAh[row * LDK + fk]);
      short8 alf = *reinterpret_cast<const short8*>(&sAl[row * LDK + fk]);
#pragma unroll
      for (int nc = 0; nc < 4; ++nc) {
        acc[mr][nc] = __builtin_amdgcn_mfma_f32_16x16x32_bf16(ahf, bhf[nc], acc[mr][nc], 0, 0, 0);
        acc[mr][nc] = __builtin_amdgcn_mfma_f32_16x16x32_bf16(ahf, blf[nc], acc[mr][nc], 0, 0, 0);
        acc[mr][nc] = __builtin_amdgcn_mfma_f32_16x16x32_bf16(alf, bhf[nc], acc[mr][nc], 0, 0, 0);
      }
    }
  }

#pragma unroll
  for (int mr = 0; mr < 4; ++mr) {
    const int rowb = m0 + wr * 64 + mr * 16 + ((lane >> 4) << 2);
#pragma unroll
    for (int nc = 0; nc < 4; ++nc) {
      const int col = n0 + wc * 64 + nc * 16 + fr;
      float* cp = C + (size_t)rowb * ldc + col;
#pragma unroll
      for (int i = 0; i < 4; ++i) cp[(size_t)i * ldc] = acc[mr][nc][i];
    }
  }
}

// ---------------------------------------------------------------------------
// Depthwise causal conv1d (K=4) + bias + SiLU
// ---------------------------------------------------------------------------
__global__ __launch_bounds__(256) void conv_silu_k(
    const float* __restrict__ proj, const float* __restrict__ ck,
    const float* __restrict__ cb, float* __restrict__ hc)
{
  const int idx = blockIdx.x * 256 + threadIdx.x;
  const int e = idx & (E_ - 1);
  const int m = idx >> 12;
  const int l = m & (L_ - 1);
  const float c0 = ck[e * 4 + 0], c1 = ck[e * 4 + 1];
  const float c2 = ck[e * 4 + 2], c3 = ck[e * 4 + 3];
  const float* pcol = proj + (size_t)m * P2E + e;
  float acc = cb[e];
  if (l >= 3) acc = fmaf(pcol[-3 * P2E], c0, acc);
  if (l >= 2) acc = fmaf(pcol[-2 * P2E], c1, acc);
  if (l >= 1) acc = fmaf(pcol[-1 * P2E], c2, acc);
  acc = fmaf(pcol[0], c3, acc);
  hc[(size_t)m * E_ + e] = siluf(acc);
}

// ---------------------------------------------------------------------------
// Chunked selective scan.
//   Block = 256 threads = 16 groups of 16 lanes; group handles (b, e, chunk).
//   Block mapping: e0 = (bid & 255)*16, c = (bid>>8)&15, b = bid>>12.
//
// Phase 1: per chunk compute transfer (P = prod a, Q = folded dBu) per lane n.
// Phase 3: combine prior chunks' (P,Q) for the entry state, re-run chunk
//          computing y = (state . C + h*D) * silu(gate), store bf16 hi/lo.
// ---------------------------------------------------------------------------
__global__ __launch_bounds__(256) void scan_p1_k(
    const float* __restrict__ hc, const float* __restrict__ ssm,
    const float* __restrict__ A_log, const float* __restrict__ dts,
    float* __restrict__ Pbuf, float* __restrict__ Qbuf)
{
  const int tid = threadIdx.x;
  const int n   = tid & 15;
  const int grp = tid >> 4;
  const int bid = blockIdx.x;
  const int e   = ((bid & 255) << 4) + grp;
  const int c   = (bid >> 8) & 15;
  const int b   = bid >> 12;
  const float Aen = -expf(A_log[e * N_ + n]);
  float P = 1.f, Q = 0.f;
  int m = b * L_ + c * CL_;
#pragma unroll 4
  for (int s = 0; s < CL_; ++s, ++m) {
    const float dt = dts[(size_t)m * E_ + e];
    const float h  = hc[(size_t)m * E_ + e];
    const float Bm = ssm[(size_t)m * SLD + TR_ + n];
    const float a  = expf(dt * Aen);
    const float bu = dt * Bm * h;
    Q = fmaf(a, Q, bu);
    P *= a;
  }
  const size_t o = (((size_t)b * CH_ + c) * E_ + e) * N_ + n;
  Pbuf[o] = P;
  Qbuf[o] = Q;
}

__global__ __launch_bounds__(256) void scan_p3_k(
    const float* __restrict__ hc, const float* __restrict__ ssm,
    const float* __restrict__ proj, const float* __restrict__ A_log,
    const float* __restrict__ Dvec, const float* __restrict__ dts,
    const float* __restrict__ Pbuf, const float* __restrict__ Qbuf,
    u16* __restrict__ yhi, u16* __restrict__ ylo)
{
  const int tid = threadIdx.x;
  const int n   = tid & 15;
  const int grp = tid >> 4;
  const int bid = blockIdx.x;
  const int e   = ((bid & 255) << 4) + grp;
  const int c   = (bid >> 8) & 15;
  const int b   = bid >> 12;
  const float Aen = -expf(A_log[e * N_ + n]);
  const float De  = Dvec[e];

  // entry state: fold chunks 0..c-1
  float state = 0.f;
  for (int cc = 0; cc < c; ++cc) {
    const size_t o = (((size_t)b * CH_ + cc) * E_ + e) * N_ + n;
    state = fmaf(Pbuf[o], state, Qbuf[o]);
  }

  int m = b * L_ + c * CL_;
#pragma unroll 4
  for (int s = 0; s < CL_; ++s, ++m) {
    const float dt = dts[(size_t)m * E_ + e];
    const float h  = hc[(size_t)m * E_ + e];
    const float Bm = ssm[(size_t)m * SLD + TR_ + n];
    const float Cm = ssm[(size_t)m * SLD + TR_ + N_ + n];
    const float a  = expf(dt * Aen);
    state = fmaf(a, state, dt * Bm * h);
    float yp = state * Cm;
    yp += __shfl_xor(yp, 1);
    yp += __shfl_xor(yp, 2);
    yp += __shfl_xor(yp, 4);
    yp += __shfl_xor(yp, 8);
    if (n == 0) {
      const float g   = proj[(size_t)m * P2E + E_ + e];
      const float res = (yp + h * De) * siluf(g);
      const u16 hv = f2bf(res);
      yhi[(size_t)m * E_ + e] = hv;
      ylo[(size_t)m * E_ + e] = f2bf(res - bf2f(hv));
    }
  }
}

// fp32-output variant of the serial scan (fallback path only)
__global__ __launch_bounds__(256) void scan_serial_k(
    const float* __restrict__ hc, const float* __restrict__ ssm,
    const float* __restrict__ proj, const float* __restrict__ A_log,
    const float* __restrict__ Dvec, const float* __restrict__ dts,
    float* __restrict__ yf)
{
  const int tid = threadIdx.x;
  const int n  = tid & 15;
  const int ge = blockIdx.x * 16 + (tid >> 4);
  const int b  = ge >> 12;
  const int e  = ge & (E_ - 1);
  const float Aen = -expf(A_log[e * N_ + n]);
  const float De  = Dvec[e];
  float state = 0.f;
  const int mbase = b * L_;
  for (int l = 0; l < L_; ++l) {
    const int m = mbase + l;
    const float dt = dts[(size_t)m * E_ + e];
    const float h  = hc[(size_t)m * E_ + e];
    const float Bm = ssm[(size_t)m * SLD + TR_ + n];
    const float Cm = ssm[(size_t)m * SLD + TR_ + N_ + n];
    state = fmaf(expf(dt * Aen), state, dt * Bm * h);
    float yp = state * Cm;
    yp += __shfl_xor(yp, 1);
    yp += __shfl_xor(yp, 2);
    yp += __shfl_xor(yp, 4);
    yp += __shfl_xor(yp, 8);
    const float g   = proj[(size_t)m * P2E + E_ + e];
    const float res = (yp + h * De) * siluf(g);
    if (n == 0) yf[(size_t)m * E_ + e] = res;
  }
}

// ---------------------------------------------------------------------------
extern "C" void kernel_launch(void* const* d_in, const int* in_sizes, int n_in,
                              void* d_out, int out_size, void* d_ws, size_t ws_size,
                              hipStream_t stream)
{
  const float* x_in  = (const float*)d_in[0];
  const float* W_in  = (const float*)d_in[1];
  const float* ck    = (const float*)d_in[2];
  const float* cb    = (const float*)d_in[3];
  const float* W_x   = (const float*)d_in[4];
  const float* W_dt  = (const float*)d_in[5];
  const float* b_dt  = (const float*)d_in[6];
  const float* W_out = (const float*)d_in[7];
  const float* A_log = (const float*)d_in[8];
  const float* Dvec  = (const float*)d_in[9];
  float* out = (float*)d_out;
  float* ws  = (float*)d_ws;

  // common fp32 workspace
  float* proj = ws;                               // 16,777,216 f (64 MB)
  float* hc   = proj + (size_t)M_ * P2E;          // 8,388,608  f (32 MB)
  float* dts  = hc   + (size_t)M_ * E_;           // 8,388,608  f (32 MB)
  float* ssm  = dts  + (size_t)M_ * E_;           // 327,680    f (1.25 MB)

  // bf16 regions, lifetime-aliased:
  //  regA (32 MB): x_hi/x_lo (dead after in-proj)  -> Wo_hi/Wo_lo
  //  regB (64 MB): Wi_hi/Wi_lo (dead after in-proj) -> y_hi/y_lo (0..32MB)
  //                                                  + Pbuf/Qbuf (32..48MB)
  u16* regA  = (u16*)(ssm + (size_t)M_ * SLD);
  u16* x_hi  = regA;
  u16* x_lo  = regA + (size_t)M_ * H_;
  u16* Wo_hi = regA;
  u16* Wo_lo = regA + (size_t)H_ * E_;
  u16* regB  = regA + 16777216;
  u16* Wi_hi = regB;
  u16* Wi_lo = regB + (size_t)P2E * H_;
  u16* y_hi  = regB;
  u16* y_lo  = regB + (size_t)M_ * E_;
  float* Pbuf = (float*)(regB + 16777216);        // 2,097,152 f (8 MB)
  float* Qbuf = Pbuf + (size_t)B_ * CH_ * E_ * N_; // 2,097,152 f (8 MB)

  const size_t need_bf =
      ((size_t)M_ * P2E + 2 * (size_t)M_ * E_ + (size_t)M_ * SLD) * 4 +
      (16777216ULL + 33554432ULL) * 2;            // = 236,191,744 B

  // x-proj accumulates with split-K atomics -> zero it every call
  hipMemsetAsync(ssm, 0, (size_t)M_ * SLD * sizeof(float), stream);

  if (ws_size >= need_bf) {
    // ---- split-bf16 MFMA path + chunked scan ----
    decomp_k<<<(M_ * H_ / 4 + 255) / 256, 256, 0, stream>>>(
        x_in, x_hi, x_lo, M_ * H_ / 4);
    wdecomp_t_k<<<dim3(P2E / 64, H_ / 64), 256, 0, stream>>>(
        W_in, Wi_hi, Wi_lo, H_, P2E);
    // 1) proj = x @ W_in   (M x 8192, K=2048)
    gemm3bf_k<<<dim3(P2E / 128, M_ / 128), 256, 0, stream>>>(
        x_hi, x_lo, Wi_hi, Wi_lo, proj, H_, P2E);
    // 2) conv + SiLU
    conv_silu_k<<<(M_ * E_) / 256, 256, 0, stream>>>(proj, ck, cb, hc);
    // 3) ssm = hc @ W_x    (split-K=8, atomic)
    sgemm_k<64,32,16,4,2,2><<<dim3(SLD/32, M_/64, 8), 256, 0, stream>>>(
        hc, W_x, ssm, E_, SLD, SLD, nullptr, E_/8);
    // 4) dts = softplus(ssm[:, :128] @ W_dt + b_dt)
    sgemm_k<128,64,16,8,4,1><<<dim3(E_/64, M_/128, 1), 256, 0, stream>>>(
        ssm, W_dt, dts, SLD, E_, E_, b_dt, TR_);
    // transpose+decompose W_out (x region dead)
    wdecomp_t_k<<<dim3(H_ / 64, E_ / 64), 256, 0, stream>>>(
        W_out, Wo_hi, Wo_lo, E_, H_);
    // 5) chunked scan: phase 1 (chunk transfers), phase 3 (combine + emit y)
    scan_p1_k<<<B_ * CH_ * (E_ / 16), 256, 0, stream>>>(
        hc, ssm, A_log, dts, Pbuf, Qbuf);
    scan_p3_k<<<B_ * CH_ * (E_ / 16), 256, 0, stream>>>(
        hc, ssm, proj, A_log, Dvec, dts, Pbuf, Qbuf, y_hi, y_lo);
    // 6) out = y @ W_out   (M x 2048, K=4096)
    gemm3bf_k<<<dim3(H_ / 128, M_ / 128), 256, 0, stream>>>(
        y_hi, y_lo, Wo_hi, Wo_lo, out, E_, H_);
  } else {
    // ---- fp32 fallback (round-1 pipeline) ----
    size_t base_f = (size_t)M_ * P2E + 2 * (size_t)M_ * E_ + (size_t)M_ * SLD;
    size_t need   = (base_f + (size_t)M_ * E_) * sizeof(float);
    float* yb = (ws_size >= need) ? (ssm + (size_t)M_ * SLD) : dts;
    sgemm_k<128,64,16,8,4,0><<<dim3(P2E/64, M_/128, 1), 256, 0, stream>>>(
        x_in, W_in, proj, H_, P2E, P2E, nullptr, H_);
    conv_silu_k<<<(M_ * E_) / 256, 256, 0, stream>>>(proj, ck, cb, hc);
    sgemm_k<64,32,16,4,2,2><<<dim3(SLD/32, M_/64, 8), 256, 0, stream>>>(
        hc, W_x, ssm, E_, SLD, SLD, nullptr, E_/8);
    sgemm_k<128,64,16,8,4,1><<<dim3(E_/64, M_/128, 1), 256, 0, stream>>>(
        ssm, W_dt, dts, SLD, E_, E_, b_dt, TR_);
    scan_serial_k<<<(B_ * E_) / 16, 256, 0, stream>>>(
        hc, ssm, proj, A_log, Dvec, dts, yb);
    sgemm_k<128,64,16,8,4,0><<<dim3(H_/64, M_/128, 1), 256, 0, stream>>>(
        yb, W_out, out, E_, H_, H_, nullptr, E_);
  }
}

// Round 4
// 797.464 us; speedup vs baseline: 3.0874x; 1.3068x over previous
//
#include <hip/hip_runtime.h>
#include <cstddef>
#include <cstdint>

// Problem constants (from reference): B,L,H,E,N,TR,K
constexpr int B_  = 2;
constexpr int L_  = 1024;
constexpr int H_  = 2048;
constexpr int E_  = 4096;
constexpr int N_  = 16;
constexpr int TR_ = 128;
constexpr int M_  = B_ * L_;        // 2048 token rows
constexpr int P2E = 2 * E_;         // 8192  (proj leading dim)
constexpr int SLD = TR_ + 2 * N_;   // 160   (ssm_p leading dim)
constexpr int CH_ = 32;             // scan chunks along L
constexpr int CL_ = L_ / CH_;       // 32 steps per chunk

typedef unsigned short u16;
using short8 = __attribute__((ext_vector_type(8))) short;
using f32x4  = __attribute__((ext_vector_type(4))) float;

__device__ __forceinline__ float siluf(float x) { return x / (1.f + expf(-x)); }
__device__ __forceinline__ float silu_fast(float x) { return x / (1.f + __expf(-x)); }
__device__ __forceinline__ float softplusf(float x) {
  return fmaxf(x, 0.f) + log1pf(expf(-fabsf(x)));
}
__device__ __forceinline__ u16 f2bf(float x) {
  union { float f; uint32_t u; } v; v.f = x;
  uint32_t r = v.u + 0x7FFFu + ((v.u >> 16) & 1u);   // RNE
  return (u16)(r >> 16);
}
__device__ __forceinline__ float bf2f(u16 h) {
  union { uint32_t u; float f; } v; v.u = ((uint32_t)h) << 16; return v.f;
}

// ---------------------------------------------------------------------------
// fp32 tiled GEMM (x-proj, dt-proj, and full-pipeline fallback)
// ---------------------------------------------------------------------------
template<int BM, int BN, int BK, int TM, int TN, int EPI>
__global__ __launch_bounds__(256) void sgemm_k(
    const float* __restrict__ A, const float* __restrict__ B,
    float* __restrict__ C, int lda, int ldb, int ldc,
    const float* __restrict__ bias, int kchunk)
{
  __shared__ float As[BK][BM + 4];
  __shared__ float Bs[BK][BN];
  const int tid = threadIdx.x;
  const int tx  = tid & 15;
  const int ty  = tid >> 4;
  const int m0  = blockIdx.y * BM;
  const int n0  = blockIdx.x * BN;
  const int k00 = blockIdx.z * kchunk;

  float acc[TM][TN];
#pragma unroll
  for (int i = 0; i < TM; ++i)
#pragma unroll
    for (int j = 0; j < TN; ++j) acc[i][j] = 0.f;

  for (int k0 = k00; k0 < k00 + kchunk; k0 += BK) {
    constexpr int A4 = BM * BK / 4;
#pragma unroll
    for (int it = 0; it < (A4 + 255) / 256; ++it) {
      int i = it * 256 + tid;
      if ((A4 % 256 == 0) || (i < A4)) {
        int row = i / (BK / 4);
        int kc  = (i % (BK / 4)) * 4;
        float4 v = *reinterpret_cast<const float4*>(
            A + (size_t)(m0 + row) * lda + k0 + kc);
        As[kc + 0][row] = v.x; As[kc + 1][row] = v.y;
        As[kc + 2][row] = v.z; As[kc + 3][row] = v.w;
      }
    }
    constexpr int B4 = BK * BN / 4;
#pragma unroll
    for (int it = 0; it < (B4 + 255) / 256; ++it) {
      int i = it * 256 + tid;
      if ((B4 % 256 == 0) || (i < B4)) {
        int kr = i / (BN / 4);
        int nc = (i % (BN / 4)) * 4;
        *reinterpret_cast<float4*>(&Bs[kr][nc]) =
            *reinterpret_cast<const float4*>(
                B + (size_t)(k0 + kr) * ldb + n0 + nc);
      }
    }
    __syncthreads();
#pragma unroll
    for (int k = 0; k < BK; ++k) {
      float a[TM], bb[TN];
      const float* ap = &As[k][ty * TM];
      if constexpr (TM == 8) {
        float4 a0 = *reinterpret_cast<const float4*>(ap);
        float4 a1 = *reinterpret_cast<const float4*>(ap + 4);
        a[0]=a0.x; a[1]=a0.y; a[2]=a0.z; a[3]=a0.w;
        a[4]=a1.x; a[5]=a1.y; a[6]=a1.z; a[7]=a1.w;
      } else {
        float4 a0 = *reinterpret_cast<const float4*>(ap);
        a[0]=a0.x; a[1]=a0.y; a[2]=a0.z; a[3]=a0.w;
      }
      const float* bp = &Bs[k][tx * TN];
      if constexpr (TN == 4) {
        float4 b0 = *reinterpret_cast<const float4*>(bp);
        bb[0]=b0.x; bb[1]=b0.y; bb[2]=b0.z; bb[3]=b0.w;
      } else {
        float2 b0 = *reinterpret_cast<const float2*>(bp);
        bb[0]=b0.x; bb[1]=b0.y;
      }
#pragma unroll
      for (int i = 0; i < TM; ++i)
#pragma unroll
        for (int j = 0; j < TN; ++j) acc[i][j] = fmaf(a[i], bb[j], acc[i][j]);
    }
    __syncthreads();
  }

#pragma unroll
  for (int i = 0; i < TM; ++i) {
    int row = m0 + ty * TM + i;
    float* crow = C + (size_t)row * ldc + n0 + tx * TN;
    if constexpr (EPI == 2) {
#pragma unroll
      for (int j = 0; j < TN; ++j) atomicAdd(&crow[j], acc[i][j]);
    } else if constexpr (EPI == 1) {
      const float* brow = bias + n0 + tx * TN;
      float4 v;
      v.x = softplusf(acc[i][0] + brow[0]);
      v.y = softplusf(acc[i][1] + brow[1]);
      v.z = softplusf(acc[i][2] + brow[2]);
      v.w = softplusf(acc[i][3] + brow[3]);
      *reinterpret_cast<float4*>(crow) = v;
    } else {
      if constexpr (TN == 4) {
        float4 v; v.x=acc[i][0]; v.y=acc[i][1]; v.z=acc[i][2]; v.w=acc[i][3];
        *reinterpret_cast<float4*>(crow) = v;
      } else {
#pragma unroll
        for (int j = 0; j < TN; ++j) crow[j] = acc[i][j];
      }
    }
  }
}

// ---------------------------------------------------------------------------
// fp32 -> (bf16 hi, bf16 lo), row-major passthrough. 4 floats / thread.
// ---------------------------------------------------------------------------
__global__ __launch_bounds__(256) void decomp_k(
    const float* __restrict__ in, u16* __restrict__ hi, u16* __restrict__ lo,
    int n4)
{
  int i = blockIdx.x * 256 + threadIdx.x;
  if (i >= n4) return;
  float4 v = *reinterpret_cast<const float4*>(in + (size_t)i * 4);
  u16 h[4], l[4];
  float x[4] = {v.x, v.y, v.z, v.w};
#pragma unroll
  for (int j = 0; j < 4; ++j) {
    h[j] = f2bf(x[j]);
    l[j] = f2bf(x[j] - bf2f(h[j]));
  }
  uint32_t h0 = h[0] | ((uint32_t)h[1] << 16), h1 = h[2] | ((uint32_t)h[3] << 16);
  uint32_t l0 = l[0] | ((uint32_t)l[1] << 16), l1 = l[2] | ((uint32_t)l[3] << 16);
  *reinterpret_cast<uint2*>(hi + (size_t)i * 4) = make_uint2(h0, h1);
  *reinterpret_cast<uint2*>(lo + (size_t)i * 4) = make_uint2(l0, l1);
}

// ---------------------------------------------------------------------------
// W[KD][ND] fp32 -> Wt_hi/Wt_lo [ND][KD] bf16 (transpose + decompose).
// ---------------------------------------------------------------------------
__global__ __launch_bounds__(256) void wdecomp_t_k(
    const float* __restrict__ W, u16* __restrict__ Whi, u16* __restrict__ Wlo,
    int KD, int ND)
{
  __shared__ float T[64][69];
  const int t  = threadIdx.x;
  const int n0 = blockIdx.x * 64;
  const int k0 = blockIdx.y * 64;
#pragma unroll
  for (int it = 0; it < 4; ++it) {
    int f  = it * 256 + t;
    int kk = f >> 4;
    int c  = (f & 15) * 4;
    float4 v = *reinterpret_cast<const float4*>(
        W + (size_t)(k0 + kk) * ND + n0 + c);
    T[kk][c] = v.x; T[kk][c+1] = v.y; T[kk][c+2] = v.z; T[kk][c+3] = v.w;
  }
  __syncthreads();
  const int nn   = t >> 2;
  const int kseg = (t & 3) * 16;
  const size_t off = (size_t)(n0 + nn) * KD + k0 + kseg;
#pragma unroll
  for (int half = 0; half < 2; ++half) {
    uint32_t hp[4], lp[4];
#pragma unroll
    for (int jj = 0; jj < 4; ++jj) {
      float x0 = T[kseg + half * 8 + jj * 2 + 0][nn];
      float x1 = T[kseg + half * 8 + jj * 2 + 1][nn];
      u16 h0 = f2bf(x0), h1 = f2bf(x1);
      u16 l0 = f2bf(x0 - bf2f(h0)), l1 = f2bf(x1 - bf2f(h1));
      hp[jj] = h0 | ((uint32_t)h1 << 16);
      lp[jj] = l0 | ((uint32_t)l1 << 16);
    }
    *reinterpret_cast<uint4*>(Whi + off + half * 8) =
        make_uint4(hp[0], hp[1], hp[2], hp[3]);
    *reinterpret_cast<uint4*>(Wlo + off + half * 8) =
        make_uint4(lp[0], lp[1], lp[2], lp[3]);
  }
}

// ---------------------------------------------------------------------------
// Split-bf16 MFMA GEMM: C[M][N] fp32 = A[M][K] x Bt[N][K]^T via
//   Ah*Bh + Ah*Bl + Al*Bh (3x mfma_f32_16x16x32_bf16, fp32 accumulate).
// ---------------------------------------------------------------------------
__global__ __launch_bounds__(256) void gemm3bf_k(
    const u16* __restrict__ Ah, const u16* __restrict__ Al,
    const u16* __restrict__ Bh, const u16* __restrict__ Bl,
    float* __restrict__ C, int K, int ldc)
{
  constexpr int BK  = 32;
  constexpr int LDK = BK + 8;
  __shared__ __align__(16) u16 sAh[128 * LDK];
  __shared__ __align__(16) u16 sAl[128 * LDK];
  __shared__ __align__(16) u16 sBh[128 * LDK];
  __shared__ __align__(16) u16 sBl[128 * LDK];

  const int tid  = threadIdx.x;
  const int lane = tid & 63;
  const int wid  = tid >> 6;
  const int wr   = wid >> 1, wc = wid & 1;
  const int m0   = blockIdx.y * 128;
  const int n0   = blockIdx.x * 128;

  const int r0 = tid >> 2;
  const int c0 = (tid & 3) * 8;

  const u16* gAh0 = Ah + (size_t)(m0 + r0) * K + c0;
  const u16* gAh1 = Ah + (size_t)(m0 + r0 + 64) * K + c0;
  const u16* gAl0 = Al + (size_t)(m0 + r0) * K + c0;
  const u16* gAl1 = Al + (size_t)(m0 + r0 + 64) * K + c0;
  const u16* gBh0 = Bh + (size_t)(n0 + r0) * K + c0;
  const u16* gBh1 = Bh + (size_t)(n0 + r0 + 64) * K + c0;
  const u16* gBl0 = Bl + (size_t)(n0 + r0) * K + c0;
  const u16* gBl1 = Bl + (size_t)(n0 + r0 + 64) * K + c0;

  const int s0 = r0 * LDK + c0;
  const int s1 = (r0 + 64) * LDK + c0;

  f32x4 acc[4][4] = {};

  const int fr = lane & 15;
  const int fk = (lane >> 4) * 8;

  for (int k0 = 0; k0 < K; k0 += BK) {
    uint4 vah0 = *reinterpret_cast<const uint4*>(gAh0 + k0);
    uint4 vah1 = *reinterpret_cast<const uint4*>(gAh1 + k0);
    uint4 val0 = *reinterpret_cast<const uint4*>(gAl0 + k0);
    uint4 val1 = *reinterpret_cast<const uint4*>(gAl1 + k0);
    uint4 vbh0 = *reinterpret_cast<const uint4*>(gBh0 + k0);
    uint4 vbh1 = *reinterpret_cast<const uint4*>(gBh1 + k0);
    uint4 vbl0 = *reinterpret_cast<const uint4*>(gBl0 + k0);
    uint4 vbl1 = *reinterpret_cast<const uint4*>(gBl1 + k0);
    __syncthreads();
    *reinterpret_cast<uint4*>(&sAh[s0]) = vah0;
    *reinterpret_cast<uint4*>(&sAh[s1]) = vah1;
    *reinterpret_cast<uint4*>(&sAl[s0]) = val0;
    *reinterpret_cast<uint4*>(&sAl[s1]) = val1;
    *reinterpret_cast<uint4*>(&sBh[s0]) = vbh0;
    *reinterpret_cast<uint4*>(&sBh[s1]) = vbh1;
    *reinterpret_cast<uint4*>(&sBl[s0]) = vbl0;
    *reinterpret_cast<uint4*>(&sBl[s1]) = vbl1;
    __syncthreads();

    short8 bhf[4], blf[4];
#pragma unroll
    for (int nc = 0; nc < 4; ++nc) {
      int row = wc * 64 + nc * 16 + fr;
      bhf[nc] = *reinterpret_cast<const short8*>(&sBh[row * LDK + fk]);
      blf[nc] = *reinterpret_cast<const short8*>(&sBl[row * LDK + fk]);
    }
#pragma unroll
    for (int mr = 0; mr < 4; ++mr) {
      int row = wr * 64 + mr * 16 + fr;
      short8 ahf = *reinterpret_cast<const short8*>(&sAh[row * LDK + fk]);
      short8 alf = *reinterpret_cast<const short8*>(&sAl[row * LDK + fk]);
#pragma unroll
      for (int nc = 0; nc < 4; ++nc) {
        acc[mr][nc] = __builtin_amdgcn_mfma_f32_16x16x32_bf16(ahf, bhf[nc], acc[mr][nc], 0, 0, 0);
        acc[mr][nc] = __builtin_amdgcn_mfma_f32_16x16x32_bf16(ahf, blf[nc], acc[mr][nc], 0, 0, 0);
        acc[mr][nc] = __builtin_amdgcn_mfma_f32_16x16x32_bf16(alf, bhf[nc], acc[mr][nc], 0, 0, 0);
      }
    }
  }

#pragma unroll
  for (int mr = 0; mr < 4; ++mr) {
    const int rowb = m0 + wr * 64 + mr * 16 + ((lane >> 4) << 2);
#pragma unroll
    for (int nc = 0; nc < 4; ++nc) {
      const int col = n0 + wc * 64 + nc * 16 + fr;
      float* cp = C + (size_t)rowb * ldc + col;
#pragma unroll
      for (int i = 0; i < 4; ++i) cp[(size_t)i * ldc] = acc[mr][nc][i];
    }
  }
}

// ---------------------------------------------------------------------------
// Depthwise causal conv1d (K=4) + bias + SiLU
// ---------------------------------------------------------------------------
__global__ __launch_bounds__(256) void conv_silu_k(
    const float* __restrict__ proj, const float* __restrict__ ck,
    const float* __restrict__ cb, float* __restrict__ hc)
{
  const int idx = blockIdx.x * 256 + threadIdx.x;
  const int e = idx & (E_ - 1);
  const int m = idx >> 12;
  const int l = m & (L_ - 1);
  const float c0 = ck[e * 4 + 0], c1 = ck[e * 4 + 1];
  const float c2 = ck[e * 4 + 2], c3 = ck[e * 4 + 3];
  const float* pcol = proj + (size_t)m * P2E + e;
  float acc = cb[e];
  if (l >= 3) acc = fmaf(pcol[-3 * P2E], c0, acc);
  if (l >= 2) acc = fmaf(pcol[-2 * P2E], c1, acc);
  if (l >= 1) acc = fmaf(pcol[-1 * P2E], c2, acc);
  acc = fmaf(pcol[0], c3, acc);
  hc[(size_t)m * E_ + e] = siluf(acc);
}

// ---------------------------------------------------------------------------
// Chunked selective scan, thread = e-channel, all N=16 states in registers.
//   Block: 256 threads = 256 consecutive e's; one (b, chunk) per block.
//   bid bits: [3:0] e-block, [8:4] chunk, [9] batch.   Grid = B*CH*(E/256).
//   B/C rows (shared by all e) staged in LDS, read as wave-uniform float4.
//   P/Q layout: [b][c][n][e]  -> coalesced stores (p1) and loads (p3 fold).
// ---------------------------------------------------------------------------
__global__ __launch_bounds__(256) void scan_p1_k(
    const float* __restrict__ hc, const float* __restrict__ ssm,
    const float* __restrict__ A_log, const float* __restrict__ dts,
    float* __restrict__ Pbuf, float* __restrict__ Qbuf)
{
  __shared__ float sB[CL_][16];
  const int tid = threadIdx.x;
  const int bid = blockIdx.x;
  const int e   = ((bid & 15) << 8) + tid;
  const int c   = (bid >> 4) & (CH_ - 1);
  const int b   = bid >> 9;
  const int m0  = b * L_ + c * CL_;

  if (tid < CL_ * 4) {
    int s = tid >> 2, q = tid & 3;
    *reinterpret_cast<float4*>(&sB[s][q * 4]) =
        *reinterpret_cast<const float4*>(
            &ssm[(size_t)(m0 + s) * SLD + TR_ + q * 4]);
  }
  __syncthreads();

  float Aen[N_];
#pragma unroll
  for (int q = 0; q < 4; ++q) {
    float4 av = *reinterpret_cast<const float4*>(&A_log[e * N_ + q * 4]);
    Aen[q*4+0] = -expf(av.x); Aen[q*4+1] = -expf(av.y);
    Aen[q*4+2] = -expf(av.z); Aen[q*4+3] = -expf(av.w);
  }

  float P[N_], Q[N_];
#pragma unroll
  for (int n = 0; n < N_; ++n) { P[n] = 1.f; Q[n] = 0.f; }

  float dt_c = dts[(size_t)m0 * E_ + e];
  float h_c  = hc [(size_t)m0 * E_ + e];
  for (int s = 0; s < CL_; ++s) {
    const int sn = (s + 1 < CL_) ? s + 1 : s;
    const float dt_n = dts[(size_t)(m0 + sn) * E_ + e];
    const float h_n  = hc [(size_t)(m0 + sn) * E_ + e];
    const float dth = dt_c * h_c;
#pragma unroll
    for (int q = 0; q < 4; ++q) {
      const float4 bv = *reinterpret_cast<const float4*>(&sB[s][q * 4]);
      const float bx[4] = {bv.x, bv.y, bv.z, bv.w};
#pragma unroll
      for (int j = 0; j < 4; ++j) {
        const int n = q * 4 + j;
        const float a = __expf(dt_c * Aen[n]);
        Q[n] = fmaf(a, Q[n], dth * bx[j]);
        P[n] *= a;
      }
    }
    dt_c = dt_n; h_c = h_n;
  }

  const size_t ob = (((size_t)b * CH_ + c) * N_) * E_ + e;
#pragma unroll
  for (int n = 0; n < N_; ++n) {
    Pbuf[ob + (size_t)n * E_] = P[n];
    Qbuf[ob + (size_t)n * E_] = Q[n];
  }
}

__global__ __launch_bounds__(256) void scan_p3_k(
    const float* __restrict__ hc, const float* __restrict__ ssm,
    const float* __restrict__ proj, const float* __restrict__ A_log,
    const float* __restrict__ Dvec, const float* __restrict__ dts,
    const float* __restrict__ Pbuf, const float* __restrict__ Qbuf,
    u16* __restrict__ yhi, u16* __restrict__ ylo)
{
  __shared__ float sBC[CL_][32];
  const int tid = threadIdx.x;
  const int bid = blockIdx.x;
  const int e   = ((bid & 15) << 8) + tid;
  const int c   = (bid >> 4) & (CH_ - 1);
  const int b   = bid >> 9;
  const int m0  = b * L_ + c * CL_;

  {
    int s = tid >> 3, q = tid & 7;
    *reinterpret_cast<float4*>(&sBC[s][q * 4]) =
        *reinterpret_cast<const float4*>(
            &ssm[(size_t)(m0 + s) * SLD + TR_ + q * 4]);
  }
  __syncthreads();

  float Aen[N_];
#pragma unroll
  for (int q = 0; q < 4; ++q) {
    float4 av = *reinterpret_cast<const float4*>(&A_log[e * N_ + q * 4]);
    Aen[q*4+0] = -expf(av.x); Aen[q*4+1] = -expf(av.y);
    Aen[q*4+2] = -expf(av.z); Aen[q*4+3] = -expf(av.w);
  }
  const float De = Dvec[e];

  // entry state: fold chunks 0..c-1  (coalesced along e)
  float st[N_];
#pragma unroll
  for (int n = 0; n < N_; ++n) st[n] = 0.f;
  for (int cc = 0; cc < c; ++cc) {
    const size_t ob = (((size_t)b * CH_ + cc) * N_) * E_ + e;
#pragma unroll
    for (int n = 0; n < N_; ++n)
      st[n] = fmaf(Pbuf[ob + (size_t)n * E_], st[n], Qbuf[ob + (size_t)n * E_]);
  }

  float dt_c = dts[(size_t)m0 * E_ + e];
  float h_c  = hc [(size_t)m0 * E_ + e];
  float g_c  = proj[(size_t)m0 * P2E + E_ + e];
  for (int s = 0; s < CL_; ++s) {
    const int sn = (s + 1 < CL_) ? s + 1 : s;
    const float dt_n = dts[(size_t)(m0 + sn) * E_ + e];
    const float h_n  = hc [(size_t)(m0 + sn) * E_ + e];
    const float g_n  = proj[(size_t)(m0 + sn) * P2E + E_ + e];
    const float dth = dt_c * h_c;
    float y = h_c * De;
#pragma unroll
    for (int q = 0; q < 4; ++q) {
      const float4 bv = *reinterpret_cast<const float4*>(&sBC[s][q * 4]);
      const float4 cv = *reinterpret_cast<const float4*>(&sBC[s][16 + q * 4]);
      const float bx[4] = {bv.x, bv.y, bv.z, bv.w};
      const float cx[4] = {cv.x, cv.y, cv.z, cv.w};
#pragma unroll
      for (int j = 0; j < 4; ++j) {
        const int n = q * 4 + j;
        const float a = __expf(dt_c * Aen[n]);
        st[n] = fmaf(a, st[n], dth * bx[j]);
        y = fmaf(st[n], cx[j], y);
      }
    }
    const float res = y * silu_fast(g_c);
    const u16 hv = f2bf(res);
    const size_t yo = (size_t)(m0 + s) * E_ + e;
    yhi[yo] = hv;
    ylo[yo] = f2bf(res - bf2f(hv));
    dt_c = dt_n; h_c = h_n; g_c = g_n;
  }
}

// fp32-output serial scan (fallback path only)
__global__ __launch_bounds__(256) void scan_serial_k(
    const float* __restrict__ hc, const float* __restrict__ ssm,
    const float* __restrict__ proj, const float* __restrict__ A_log,
    const float* __restrict__ Dvec, const float* __restrict__ dts,
    float* __restrict__ yf)
{
  const int tid = threadIdx.x;
  const int n  = tid & 15;
  const int ge = blockIdx.x * 16 + (tid >> 4);
  const int b  = ge >> 12;
  const int e  = ge & (E_ - 1);
  const float Aen = -expf(A_log[e * N_ + n]);
  const float De  = Dvec[e];
  float state = 0.f;
  const int mbase = b * L_;
  for (int l = 0; l < L_; ++l) {
    const int m = mbase + l;
    const float dt = dts[(size_t)m * E_ + e];
    const float h  = hc[(size_t)m * E_ + e];
    const float Bm = ssm[(size_t)m * SLD + TR_ + n];
    const float Cm = ssm[(size_t)m * SLD + TR_ + N_ + n];
    state = fmaf(expf(dt * Aen), state, dt * Bm * h);
    float yp = state * Cm;
    yp += __shfl_xor(yp, 1);
    yp += __shfl_xor(yp, 2);
    yp += __shfl_xor(yp, 4);
    yp += __shfl_xor(yp, 8);
    const float g   = proj[(size_t)m * P2E + E_ + e];
    const float res = (yp + h * De) * siluf(g);
    if (n == 0) yf[(size_t)m * E_ + e] = res;
  }
}

// ---------------------------------------------------------------------------
extern "C" void kernel_launch(void* const* d_in, const int* in_sizes, int n_in,
                              void* d_out, int out_size, void* d_ws, size_t ws_size,
                              hipStream_t stream)
{
  const float* x_in  = (const float*)d_in[0];
  const float* W_in  = (const float*)d_in[1];
  const float* ck    = (const float*)d_in[2];
  const float* cb    = (const float*)d_in[3];
  const float* W_x   = (const float*)d_in[4];
  const float* W_dt  = (const float*)d_in[5];
  const float* b_dt  = (const float*)d_in[6];
  const float* W_out = (const float*)d_in[7];
  const float* A_log = (const float*)d_in[8];
  const float* Dvec  = (const float*)d_in[9];
  float* out = (float*)d_out;
  float* ws  = (float*)d_ws;

  // common fp32 workspace
  float* proj = ws;                               // 16,777,216 f (64 MB)
  float* hc   = proj + (size_t)M_ * P2E;          // 8,388,608  f (32 MB)
  float* dts  = hc   + (size_t)M_ * E_;           // 8,388,608  f (32 MB)
  float* ssm  = dts  + (size_t)M_ * E_;           // 327,680    f (1.25 MB)

  // bf16 regions, lifetime-aliased:
  //  regA (32 MB): x_hi/x_lo (dead after in-proj)  -> Wo_hi/Wo_lo
  //  regB (64 MB): Wi_hi/Wi_lo (dead after in-proj) -> y_hi/y_lo (0..32MB)
  //                                                  + Pbuf/Qbuf (32..64MB)
  u16* regA  = (u16*)(ssm + (size_t)M_ * SLD);
  u16* x_hi  = regA;
  u16* x_lo  = regA + (size_t)M_ * H_;
  u16* Wo_hi = regA;
  u16* Wo_lo = regA + (size_t)H_ * E_;
  u16* regB  = regA + 16777216;
  u16* Wi_hi = regB;
  u16* Wi_lo = regB + (size_t)P2E * H_;
  u16* y_hi  = regB;
  u16* y_lo  = regB + (size_t)M_ * E_;
  float* Pbuf = (float*)(regB + 16777216);         // 4,194,304 f (16 MB)
  float* Qbuf = Pbuf + (size_t)B_ * CH_ * E_ * N_; // 4,194,304 f (16 MB)

  const size_t need_bf =
      ((size_t)M_ * P2E + 2 * (size_t)M_ * E_ + (size_t)M_ * SLD) * 4 +
      (16777216ULL + 33554432ULL) * 2;            // = 236,191,744 B

  // x-proj accumulates with split-K atomics -> zero it every call
  hipMemsetAsync(ssm, 0, (size_t)M_ * SLD * sizeof(float), stream);

  if (ws_size >= need_bf) {
    // ---- split-bf16 MFMA path + register-state chunked scan ----
    decomp_k<<<(M_ * H_ / 4 + 255) / 256, 256, 0, stream>>>(
        x_in, x_hi, x_lo, M_ * H_ / 4);
    wdecomp_t_k<<<dim3(P2E / 64, H_ / 64), 256, 0, stream>>>(
        W_in, Wi_hi, Wi_lo, H_, P2E);
    // 1) proj = x @ W_in   (M x 8192, K=2048)
    gemm3bf_k<<<dim3(P2E / 128, M_ / 128), 256, 0, stream>>>(
        x_hi, x_lo, Wi_hi, Wi_lo, proj, H_, P2E);
    // 2) conv + SiLU
    conv_silu_k<<<(M_ * E_) / 256, 256, 0, stream>>>(proj, ck, cb, hc);
    // 3) ssm = hc @ W_x    (split-K=8, atomic)
    sgemm_k<64,32,16,4,2,2><<<dim3(SLD/32, M_/64, 8), 256, 0, stream>>>(
        hc, W_x, ssm, E_, SLD, SLD, nullptr, E_/8);
    // 4) dts = softplus(ssm[:, :128] @ W_dt + b_dt)
    sgemm_k<128,64,16,8,4,1><<<dim3(E_/64, M_/128, 1), 256, 0, stream>>>(
        ssm, W_dt, dts, SLD, E_, E_, b_dt, TR_);
    // transpose+decompose W_out (x region dead)
    wdecomp_t_k<<<dim3(H_ / 64, E_ / 64), 256, 0, stream>>>(
        W_out, Wo_hi, Wo_lo, E_, H_);
    // 5) chunked scan: phase 1 (chunk transfers), phase 3 (combine + emit y)
    scan_p1_k<<<B_ * CH_ * (E_ / 256), 256, 0, stream>>>(
        hc, ssm, A_log, dts, Pbuf, Qbuf);
    scan_p3_k<<<B_ * CH_ * (E_ / 256), 256, 0, stream>>>(
        hc, ssm, proj, A_log, Dvec, dts, Pbuf, Qbuf, y_hi, y_lo);
    // 6) out = y @ W_out   (M x 2048, K=4096)
    gemm3bf_k<<<dim3(H_ / 128, M_ / 128), 256, 0, stream>>>(
        y_hi, y_lo, Wo_hi, Wo_lo, out, E_, H_);
  } else {
    // ---- fp32 fallback (round-1 pipeline) ----
    size_t base_f = (size_t)M_ * P2E + 2 * (size_t)M_ * E_ + (size_t)M_ * SLD;
    size_t need   = (base_f + (size_t)M_ * E_) * sizeof(float);
    float* yb = (ws_size >= need) ? (ssm + (size_t)M_ * SLD) : dts;
    sgemm_k<128,64,16,8,4,0><<<dim3(P2E/64, M_/128, 1), 256, 0, stream>>>(
        x_in, W_in, proj, H_, P2E, P2E, nullptr, H_);
    conv_silu_k<<<(M_ * E_) / 256, 256, 0, stream>>>(proj, ck, cb, hc);
    sgemm_k<64,32,16,4,2,2><<<dim3(SLD/32, M_/64, 8), 256, 0, stream>>>(
        hc, W_x, ssm, E_, SLD, SLD, nullptr, E_/8);
    sgemm_k<128,64,16,8,4,1><<<dim3(E_/64, M_/128, 1), 256, 0, stream>>>(
        ssm, W_dt, dts, SLD, E_, E_, b_dt, TR_);
    scan_serial_k<<<(B_ * E_) / 16, 256, 0, stream>>>(
        hc, ssm, proj, A_log, Dvec, dts, yb);
    sgemm_k<128,64,16,8,4,0><<<dim3(H_/64, M_/128, 1), 256, 0, stream>>>(
        yb, W_out, out, E_, H_, H_, nullptr, E_);
  }
}